// Round 7
// baseline (231.742 us; speedup 1.0000x reference)
//
#include <hip/hip_runtime.h>

// LIF forward: x [B=32, T=16, N=65536] f32, thresh scalar f32 -> spikes [B,T,N] f32
//   mem = mem*TAU + x[t];  spike = (mem > thresh);  mem = spike ? 0 : mem;
//
// R1:  VGPR=20, ~1 load in flight/wave, 2.5 TB/s (fill kernel: 6.7). latency-bound.
// R2:  preload array -> scheduler re-sank loads. no change.
// R5:  sched_barrier(0) -> no change (VGPR 24).
// R6:  per-t asm pins -> FAILED: pins only order pin_t after load_t; compiler
//      scheduled load0,pin0,compute0,load1,pin1,... = still serial. VGPR 20.
// R7:  ONE volatile asm consuming ALL 16 load results ("+v" x16 on f32x2).
//      Every load is a data-dependence of the single pin -> all 16 must issue
//      before it; one vmcnt(0) drain; 32 data VGPRs forced live. Enforced by
//      SSA data flow -- no scheduling freedom left.

#define TAU 0.25f

typedef float f32x2 __attribute__((ext_vector_type(2)));

__global__ __launch_bounds__(256, 8) void lif_fwd_kernel(
    const f32x2* __restrict__ x,
    const float* __restrict__ thresh,
    f32x2* __restrict__ out)
{
    constexpr int T  = 16;
    constexpr int N2 = 65536 / 2;   // 32768 float2 per (b,t) row

    const int gid = blockIdx.x * blockDim.x + threadIdx.x;  // 0 .. B*N2-1
    const int b   = gid >> 15;          // gid / N2
    const int n2  = gid & (N2 - 1);     // gid % N2

    const float th = thresh[0];

    const size_t base = (size_t)b * T * N2 + n2;
    const f32x2* xp = x   + base;
    f32x2*       op = out + base;

    // Issue all 16 independent loads.
    f32x2 xt[T];
#pragma unroll
    for (int t = 0; t < T; ++t)
        xt[t] = xp[(size_t)t * N2];

    // Mega-pin: single volatile asm reads+redefines ALL 16 results. All loads
    // must issue before this point (data deps of one instruction); compiler
    // emits one s_waitcnt vmcnt(0) here; 32 data VGPRs live across it.
    asm volatile(""
        : "+v"(xt[0]),  "+v"(xt[1]),  "+v"(xt[2]),  "+v"(xt[3]),
          "+v"(xt[4]),  "+v"(xt[5]),  "+v"(xt[6]),  "+v"(xt[7]),
          "+v"(xt[8]),  "+v"(xt[9]),  "+v"(xt[10]), "+v"(xt[11]),
          "+v"(xt[12]), "+v"(xt[13]), "+v"(xt[14]), "+v"(xt[15]));

    float mx = 0.f, my = 0.f;

#pragma unroll
    for (int t = 0; t < T; ++t) {
        mx = mx * TAU + xt[t].x;
        my = my * TAU + xt[t].y;

        const bool px = mx > th;
        const bool py = my > th;

        f32x2 s;
        s.x = px ? 1.f : 0.f;
        s.y = py ? 1.f : 0.f;

        mx = px ? 0.f : mx;
        my = py ? 0.f : my;

        // Output never re-read: non-temporal keeps L2/L3 for the x stream.
        __builtin_nontemporal_store(s, &op[(size_t)t * N2]);
    }
}

extern "C" void kernel_launch(void* const* d_in, const int* in_sizes, int n_in,
                              void* d_out, int out_size, void* d_ws, size_t ws_size,
                              hipStream_t stream)
{
    const float* x      = (const float*)d_in[0];
    const float* thresh = (const float*)d_in[1];
    float*       out    = (float*)d_out;

    // total = B*T*N = 33,554,432 ; threads = B*N/2 = total/(16*2) = 1,048,576
    const int total   = in_sizes[0];
    const int threads = total / (16 * 2);
    const int block   = 256;
    const int grid    = threads / block;   // 4096 blocks

    lif_fwd_kernel<<<grid, block, 0, stream>>>(
        (const f32x2*)x, thresh, (f32x2*)out);
}

// Round 8
// 231.153 us; speedup vs baseline: 1.0025x; 1.0025x over previous
//
#include <hip/hip_runtime.h>

// LIF forward: x [B=32, T=16, N=65536] f32, thresh scalar f32 -> spikes [B,T,N] f32
//   mem = mem*TAU + x[t];  spike = (mem > thresh);  mem = spike ? 0 : mem;
//
// R1:  direct loads, VGPR=20 -> ~2 loads in flight, 2.5 TB/s. latency-bound.
// R2/R5/R6/R7: four attempts to force 16 register-destination loads in flight
//   (preload array / sched_barrier / per-t pins / one mega-pin asm) ALL came
//   back VGPR=20-24, 2.5 TB/s. The backend always re-serializes loads that
//   have VGPR destinations. (R7's VGPR=20 is impossible with the mega-pin ->
//   it was optimized out of existence somehow; stop fighting this.)
// R8:  destination-free loads: global_load_lds is fire-and-forget (no VGPR
//   result, ordered like a store) -> compiler CANNOT serialize it. 16 issued
//   back-to-back = 16 KB in flight/wave. Block = 256 thr, 64 KB LDS tile
//   [16 t][1024 floats]. Each wave's loads fill its own 1 KB row-chunks, so
//   no cross-wave barrier: one vmcnt(0), then ds_read_b128 (conflict-free,
//   contiguous per lane) + compute + nontemporal coalesced stores.

#define TAU 0.25f

typedef float f32x4 __attribute__((ext_vector_type(4)));

__global__ __launch_bounds__(256) void lif_fwd_kernel(
    const float* __restrict__ x,
    const float* __restrict__ thresh,
    float* __restrict__ out)
{
    constexpr int T    = 16;
    constexpr int N    = 65536;
    constexpr int TILE = 1024;                // floats per t-row per block

    __shared__ float lds[T * TILE];           // 64 KB -> 2 blocks/CU

    const int tid  = threadIdx.x;
    const int wave = tid >> 6;
    const int lane = tid & 63;

    const int tile_idx = blockIdx.x & 63;     // 65536/1024 = 64 tiles per b
    const int b        = blockIdx.x >> 6;

    const size_t row0 = (size_t)b * T * N + (size_t)tile_idx * TILE;

    // 16 independent fire-and-forget DMA loads: global -> LDS, no VGPR dest.
    // LDS dest is wave-uniform; HW scatters lane i at dest + i*16 (matches
    // the per-lane global addr row + wave*256 + lane*4 floats).
#pragma unroll
    for (int t = 0; t < T; ++t) {
        const float* gsrc = x + row0 + (size_t)t * N + wave * 256 + lane * 4;
        float*       ldst = lds + t * TILE + wave * 256;
        __builtin_amdgcn_global_load_lds(
            (const __attribute__((address_space(1))) void*)gsrc,
            (__attribute__((address_space(3))) void*)ldst,
            16, 0, 0);
    }

    // Drain all 16 loads (own-wave data only -> no __syncthreads needed).
    asm volatile("s_waitcnt vmcnt(0)" ::: "memory");
    __builtin_amdgcn_sched_barrier(0);

    const float th  = thresh[0];
    const int   col = tid * 4;                // this thread's float4 column

    f32x4 mem = {0.f, 0.f, 0.f, 0.f};

#pragma unroll
    for (int t = 0; t < T; ++t) {
        f32x4 xt = *(const f32x4*)(lds + t * TILE + col);  // ds_read_b128

        mem.x = mem.x * TAU + xt.x;
        mem.y = mem.y * TAU + xt.y;
        mem.z = mem.z * TAU + xt.z;
        mem.w = mem.w * TAU + xt.w;

        const bool px = mem.x > th;
        const bool py = mem.y > th;
        const bool pz = mem.z > th;
        const bool pw = mem.w > th;

        f32x4 s;
        s.x = px ? 1.f : 0.f;
        s.y = py ? 1.f : 0.f;
        s.z = pz ? 1.f : 0.f;
        s.w = pw ? 1.f : 0.f;

        mem.x = px ? 0.f : mem.x;
        mem.y = py ? 0.f : mem.y;
        mem.z = pz ? 0.f : mem.z;
        mem.w = pw ? 0.f : mem.w;

        // Output never re-read: keep L2/L3 for the x stream.
        __builtin_nontemporal_store(s, (f32x4*)(out + row0 + (size_t)t * N + col));
    }
}

extern "C" void kernel_launch(void* const* d_in, const int* in_sizes, int n_in,
                              void* d_out, int out_size, void* d_ws, size_t ws_size,
                              hipStream_t stream)
{
    const float* x      = (const float*)d_in[0];
    const float* thresh = (const float*)d_in[1];
    float*       out    = (float*)d_out;

    // total = B*T*N = 33,554,432 ; blocks = total / (T*TILE) = 2048
    const int total = in_sizes[0];
    const int grid  = total / (16 * 1024);
    const int block = 256;

    lif_fwd_kernel<<<grid, block, 0, stream>>>(x, thresh, out);
}